// Round 5
// baseline (173.233 us; speedup 1.0000x reference)
//
#include <hip/hip_runtime.h>
#include <math.h>

#define VOCAB 50257
#define EMB   128
#define CTX   200
#define CHUNK 128
#define NCHUNK 393                    // ceil(VOCAB/128)
#define NT    ((VOCAB + 15) / 16)     // 3142 row-tiles of 16
#define K3_BLOCKS 394

// ---------------- K12: fused column-sum + hidden partial --------------------
// grid 393 x 128 threads. Block b owns columns [128b, 128b+128).
// Phase A: each thread sums its column of X over all 200 rows (registers).
// Phase B: hpart[b][e] = sum_{cols in slab} sv[col] * Wq[e, col]
//   wave w (2 waves) handles e = 64w..64w+63; lane l covers cols l and l+64
//   (two 256B coalesced Wq segments per e); 6-step shuffle reduce per e.
__global__ __launch_bounds__(128)
void k12(const float* __restrict__ X, const float* __restrict__ Wq,
         float* __restrict__ hpart) {
    __shared__ float svs[CHUNK];
    __shared__ float hres[EMB];
    const int b = blockIdx.x, t = threadIdx.x;
    const int c0 = b * CHUNK;
    const int v  = c0 + t;

    // Phase A: column sum, 10 outstanding loads for MLP
    float sv = 0.f;
    if (v < VOCAB) {
        const float* p = X + v;
        float a0=0.f,a1=0.f,a2=0.f,a3=0.f,a4=0.f,a5=0.f,a6=0.f,a7=0.f,a8=0.f,a9=0.f;
        for (int i = 0; i < CTX / 10; ++i) {        // 20 iters x 10 rows
            a0 += p[0 * (size_t)VOCAB];
            a1 += p[1 * (size_t)VOCAB];
            a2 += p[2 * (size_t)VOCAB];
            a3 += p[3 * (size_t)VOCAB];
            a4 += p[4 * (size_t)VOCAB];
            a5 += p[5 * (size_t)VOCAB];
            a6 += p[6 * (size_t)VOCAB];
            a7 += p[7 * (size_t)VOCAB];
            a8 += p[8 * (size_t)VOCAB];
            a9 += p[9 * (size_t)VOCAB];
            p += 10 * (size_t)VOCAB;
        }
        sv = (((a0 + a1) + (a2 + a3)) + ((a4 + a5) + (a6 + a7))) + (a8 + a9);
    }
    svs[t] = sv;
    __syncthreads();

    // Phase B: dot against Wq slab
    const int w = t >> 6, l = t & 63;
    const float s_lo = svs[l], s_hi = svs[l + 64];
    const bool full = (c0 + CHUNK <= VOCAB);
#pragma unroll 4
    for (int i = 0; i < 64; ++i) {
        int e = w * 64 + i;
        const float* row = Wq + (size_t)e * VOCAB + c0;
        float w0, w1;
        if (full) { w0 = row[l]; w1 = row[l + 64]; }
        else {
            w0 = (c0 + l      < VOCAB) ? row[l]      : 0.f;
            w1 = (c0 + l + 64 < VOCAB) ? row[l + 64] : 0.f;
        }
        float acc = w0 * s_lo + w1 * s_hi;
        acc += __shfl_xor(acc, 1, 64);
        acc += __shfl_xor(acc, 2, 64);
        acc += __shfl_xor(acc, 4, 64);
        acc += __shfl_xor(acc, 8, 64);
        acc += __shfl_xor(acc, 16, 64);
        acc += __shfl_xor(acc, 32, 64);
        if (l == 0) hres[e] = acc;
    }
    __syncthreads();
    hpart[(size_t)b * EMB + t] = hres[t];    // 128 threads = 128 e values
}

// ---------------- K3: logits + per-block exp partial (no atomics) -----------
// grid K3_BLOCKS x 256. h built per-block from the 393 hpart chunks (L2-hot,
// coalesced 512B per chunk). Then 16 lanes per row v, two float4 loads per
// lane over the contiguous 512B Ww row.
__global__ __launch_bounds__(256)
void k3(const float* __restrict__ Ww, const float* __restrict__ bw,
        const float* __restrict__ hpart, const float* __restrict__ bq,
        const int* __restrict__ lenp,
        float* __restrict__ logits, float* __restrict__ partials) {
    __shared__ float h[EMB];
    __shared__ float wsum[4];
    const int t = threadIdx.x, b = blockIdx.x;
    if (t < EMB) {
        float h0=0.f, h1=0.f, h2=0.f, h3=0.f;
        int c = 0;
        for (; c + 4 <= NCHUNK; c += 4) {
            h0 += hpart[(c + 0) * EMB + t];
            h1 += hpart[(c + 1) * EMB + t];
            h2 += hpart[(c + 2) * EMB + t];
            h3 += hpart[(c + 3) * EMB + t];
        }
        for (; c < NCHUNK; ++c) h0 += hpart[c * EMB + t];
        float hr = (h0 + h1) + (h2 + h3);
        float len = (float)lenp[0];
        h[t] = (hr + (float)CTX * bq[t]) / len;
    }
    __syncthreads();

    int group = t >> 4;                   // row within 16-row tile
    int c     = t & 15;                   // lane within row
    float eacc = 0.f;
    for (int tile = b; tile < NT; tile += K3_BLOCKS) {
        int v = tile * 16 + group;
        float acc = 0.f;
        if (v < VOCAB) {
            const float4* row = (const float4*)(Ww + (size_t)v * EMB);
            float4 w0 = row[c * 2];
            float4 w1 = row[c * 2 + 1];
            const float* hp = h + c * 8;
            acc = w0.x * hp[0] + w0.y * hp[1] + w0.z * hp[2] + w0.w * hp[3]
                + w1.x * hp[4] + w1.y * hp[5] + w1.z * hp[6] + w1.w * hp[7];
        }
        acc += __shfl_xor(acc, 1, 64);
        acc += __shfl_xor(acc, 2, 64);
        acc += __shfl_xor(acc, 4, 64);
        acc += __shfl_xor(acc, 8, 64);
        if (v < VOCAB && c == 0) {
            float lg = acc + bw[v];
            logits[v] = lg;
            eacc += expf(lg);
        }
    }

    for (int off = 32; off > 0; off >>= 1) eacc += __shfl_down(eacc, off, 64);
    int lane = t & 63, wid = t >> 6;
    if (lane == 0) wsum[wid] = eacc;
    __syncthreads();
    if (t == 0)
        partials[b] = (wsum[0] + wsum[1]) + (wsum[2] + wsum[3]);
}

// ---------------- K4: out[v] = logits[v] - log(sum partials) ----------------
__global__ __launch_bounds__(256)
void k4(const float* __restrict__ logits, const float* __restrict__ partials,
        float* __restrict__ out) {
    __shared__ float wsum[4];
    __shared__ float lz;
    float acc = 0.f;
    for (int i = threadIdx.x; i < K3_BLOCKS; i += 256) acc += partials[i];
    for (int off = 32; off > 0; off >>= 1) acc += __shfl_down(acc, off, 64);
    int lane = threadIdx.x & 63, wid = threadIdx.x >> 6;
    if (lane == 0) wsum[wid] = acc;
    __syncthreads();
    if (threadIdx.x == 0)
        lz = logf((wsum[0] + wsum[1]) + (wsum[2] + wsum[3]));
    __syncthreads();
    int v = blockIdx.x * 256 + threadIdx.x;
    if (v < VOCAB) out[v] = logits[v] - lz;
}

extern "C" void kernel_launch(void* const* d_in, const int* in_sizes, int n_in,
                              void* d_out, int out_size, void* d_ws, size_t ws_size,
                              hipStream_t stream) {
    const float* X    = (const float*)d_in[0];   // [CTX, VOCAB]
    const int*   lenp = (const int*)d_in[1];     // scalar 200
    const float* Wq   = (const float*)d_in[2];   // [EMB, VOCAB]
    const float* bq   = (const float*)d_in[3];   // [EMB]
    const float* Ww   = (const float*)d_in[4];   // [VOCAB, EMB]
    const float* bw   = (const float*)d_in[5];   // [VOCAB]
    float* out = (float*)d_out;                  // [VOCAB]

    // Workspace (floats), all plain stores, nothing needs zeroing:
    //   [0, 50304)            hpart [393][128]
    //   [50304, 50698)        partials [394]
    //   [51200, 51200+VOCAB)  logits
    float* ws       = (float*)d_ws;
    float* hpart    = ws;
    float* partials = ws + NCHUNK * EMB;
    float* logits   = ws + 51200;

    k12<<<NCHUNK, CHUNK, 0, stream>>>(X, Wq, hpart);
    k3<<<K3_BLOCKS, 256, 0, stream>>>(Ww, bw, hpart, bq, lenp, logits, partials);
    k4<<<(VOCAB + 255) / 256, 256, 0, stream>>>(logits, partials, out);
}